// Round 1
// baseline (369.402 us; speedup 1.0000x reference)
//
#include <hip/hip_runtime.h>
#include <math.h>

// SingleRoIExtractor: 4-level FPN RoIAlign (mmdet legacy semantics, aligned=False)
// feats: [2,256,H,W] fp32 at H,W = (200,304),(100,152),(50,76),(25,38)
// rois:  [K,5] (batch, x1,y1,x2,y2); out: [K,256,7,7] fp32
// OUT_SIZE=7, SAMPLE_NUM=2, FINEST_SCALE=56, STRIDES=(4,8,16,32)

#define OUT_SZ 7
#define NCH 256
#define NBINS 49   // 7*7

struct RoiParam {
    int   lvl;
    int   batch;
    float x1, y1;    // scaled roi origin
    float bw, bh;    // bin sizes (scaled roi extent / 7)
    int   H, W;      // feature dims at selected level
};  // 32 bytes

__global__ __launch_bounds__(256)
void roi_param_kernel(const float* __restrict__ rois, int K, RoiParam* __restrict__ p)
{
    int k = blockIdx.x * blockDim.x + threadIdx.x;
    if (k >= K) return;
    float b  = rois[k * 5 + 0];
    float x1 = rois[k * 5 + 1];
    float y1 = rois[k * 5 + 2];
    float x2 = rois[k * 5 + 3];
    float y2 = rois[k * 5 + 4];

    // map_roi_levels: scale = sqrt((x2-x1+1)*(y2-y1+1)); lvl = clip(floor(log2(scale/56+1e-6)),0,3)
    float scale = sqrtf((x2 - x1 + 1.0f) * (y2 - y1 + 1.0f));
    int lvl = (int)floorf(log2f(scale * (1.0f / 56.0f) + 1e-6f));
    lvl = lvl < 0 ? 0 : (lvl > 3 ? 3 : lvl);

    float ss = 1.0f / (float)(4 << lvl);   // 1/4, 1/8, 1/16, 1/32 (exact in fp32)
    float sx1 = x1 * ss, sy1 = y1 * ss;
    float sx2 = x2 * ss, sy2 = y2 * ss;
    float rw = fmaxf(sx2 - sx1, 1.0f);
    float rh = fmaxf(sy2 - sy1, 1.0f);

    RoiParam rp;
    rp.lvl   = lvl;
    rp.batch = (int)b;
    rp.x1 = sx1;
    rp.y1 = sy1;
    rp.bw = rw * (1.0f / OUT_SZ);
    rp.bh = rh * (1.0f / OUT_SZ);
    rp.H  = 800  >> (2 + lvl);   // 200,100,50,25
    rp.W  = 1216 >> (2 + lvl);   // 304,152,76,38
    p[k] = rp;
}

__global__ __launch_bounds__(256)
void roi_align_kernel(const float* __restrict__ f0, const float* __restrict__ f1,
                      const float* __restrict__ f2, const float* __restrict__ f3,
                      const RoiParam* __restrict__ params,
                      float* __restrict__ out, int total)
{
    int i = blockIdx.x * 256 + threadIdx.x;
    if (i >= total) return;

    int bin = i % NBINS;
    int kc  = i / NBINS;
    int c   = kc % NCH;
    int k   = kc / NCH;
    int oy  = bin / OUT_SZ;
    int ox  = bin % OUT_SZ;

    RoiParam rp = params[k];
    int H = rp.H, W = rp.W;
    float fH = (float)H, fW = (float)W;

    const float* fb = (rp.lvl == 0) ? f0 : (rp.lvl == 1) ? f1 : (rp.lvl == 2) ? f2 : f3;
    const float* fc = fb + (size_t)(rp.batch * NCH + c) * (size_t)(H * W);

    // two sample positions per axis (sample_num = 2), shared across the 2x2 grid
    int   y0i[2], y1i[2];
    float wy0[2], wy1[2];
    bool  vy[2];
#pragma unroll
    for (int s = 0; s < 2; ++s) {
        float y = rp.y1 + ((float)(2 * oy + s) + 0.5f) * 0.5f * rp.bh;
        vy[s] = (y >= -1.0f) && (y <= fH);
        float yc = fminf(fmaxf(y, 0.0f), fH - 1.0f);
        float yf = floorf(yc);
        int   y0 = (int)yf;
        float ly = yc - yf;
        y0i[s] = y0;
        y1i[s] = (y0 + 1 < H) ? (y0 + 1) : (H - 1);
        wy1[s] = ly;
        wy0[s] = 1.0f - ly;
    }

    int   x0i[2], x1i[2];
    float wx0[2], wx1[2];
    bool  vx[2];
#pragma unroll
    for (int s = 0; s < 2; ++s) {
        float x = rp.x1 + ((float)(2 * ox + s) + 0.5f) * 0.5f * rp.bw;
        vx[s] = (x >= -1.0f) && (x <= fW);
        float xc = fminf(fmaxf(x, 0.0f), fW - 1.0f);
        float xf = floorf(xc);
        int   x0 = (int)xf;
        float lx = xc - xf;
        x0i[s] = x0;
        x1i[s] = (x0 + 1 < W) ? (x0 + 1) : (W - 1);
        wx1[s] = lx;
        wx0[s] = 1.0f - lx;
    }

    float acc = 0.0f;
#pragma unroll
    for (int sy = 0; sy < 2; ++sy) {
#pragma unroll
        for (int sx = 0; sx < 2; ++sx) {
            if (vy[sy] && vx[sx]) {
                const float* r0 = fc + (size_t)y0i[sy] * W;
                const float* r1 = fc + (size_t)y1i[sy] * W;
                float v00 = r0[x0i[sx]];
                float v01 = r0[x1i[sx]];
                float v10 = r1[x0i[sx]];
                float v11 = r1[x1i[sx]];
                acc += v00 * (wy0[sy] * wx0[sx]) + v01 * (wy0[sy] * wx1[sx])
                     + v10 * (wy1[sy] * wx0[sx]) + v11 * (wy1[sy] * wx1[sx]);
            }
        }
    }
    out[i] = acc * 0.25f;
}

extern "C" void kernel_launch(void* const* d_in, const int* in_sizes, int n_in,
                              void* d_out, int out_size, void* d_ws, size_t ws_size,
                              hipStream_t stream)
{
    const float* f0   = (const float*)d_in[0];
    const float* f1   = (const float*)d_in[1];
    const float* f2   = (const float*)d_in[2];
    const float* f3   = (const float*)d_in[3];
    const float* rois = (const float*)d_in[4];
    float* out = (float*)d_out;

    int K = in_sizes[4] / 5;
    if (K <= 0) return;

    RoiParam* params = (RoiParam*)d_ws;   // K * 32 bytes (32 KB for K=1024)

    int pb = (K + 255) / 256;
    roi_param_kernel<<<pb, 256, 0, stream>>>(rois, K, params);

    int total = K * NCH * NBINS;
    int blocks = (total + 255) / 256;
    roi_align_kernel<<<blocks, 256, 0, stream>>>(f0, f1, f2, f3, params, out, total);
}